// Round 3
// baseline (262.688 us; speedup 1.0000x reference)
//
#include <hip/hip_runtime.h>

// Lowpass IIR scan: level[t] = (1-s)*x[t] + s*level[t-1], s = sigmoid(smooth).
// Chunked-scan (C=32 chunks of L=64) + float4 vectorization along U:
//   each lane owns 4 adjacent chains -> 16B loads/stores per step
//   (1 KiB per wave per instruction; D=16 prefetch -> 16KB in flight/wave).
// K1: per-chunk partial finals P_c (zero-init scan), pure streaming read.
// K2: entry level via P-lookback (entry = P_i + s^L * entry), scan + store.

constexpr int B  = 16;
constexpr int T  = 2048;
constexpr int U  = 1024;
constexpr int C  = 32;       // chunks along T
constexpr int L  = T / C;    // 64
constexpr int D  = 16;       // float4 prefetch depth (L % D == 0)
constexpr int U4 = U / 4;    // 256 float4 per row
constexpr int G  = B * (U / 256);  // 64 chain-groups (wave covers 256 u's)
constexpr int P4N = B * U / 4;     // 4096 float4 per chunk in P

__device__ __forceinline__ float sigmoidf(float x) {
    return 1.0f / (1.0f + __expf(-x));
}

// ---- Kernel 1: per-chunk partial finals (init = 0) ----
__global__ __launch_bounds__(64, 2) void lowpass_partial(
    const float4* __restrict__ in4,     // [B*T*U4]
    const float4* __restrict__ smooth4, // [U4]
    float4* __restrict__ P4)            // [C * P4N]
{
    const int lane = threadIdx.x;          // 0..63
    const int blk  = blockIdx.x;           // 0..C*G-1
    const int c    = blk >> 6;             // chunk (G=64)
    const int g    = blk & 63;             // chain-group
    const int b    = g >> 2;
    const int ublk = g & 3;
    const int u4   = ublk * 64 + lane;     // float4 column index

    const float4 smv = smooth4[u4];
    const float sx = sigmoidf(smv.x), sy = sigmoidf(smv.y),
                sz = sigmoidf(smv.z), sw = sigmoidf(smv.w);
    const float ox = 1.0f - sx, oy = 1.0f - sy, oz = 1.0f - sz, ow = 1.0f - sw;

    const float4* __restrict__ ip =
        in4 + ((size_t)b * T + (size_t)c * L) * U4 + u4;

    float lx = 0.f, ly = 0.f, lz = 0.f, lw = 0.f;
    float4 buf[D];
    #pragma unroll
    for (int i = 0; i < D; ++i) buf[i] = ip[(size_t)i * U4];

    int t = 0;
    for (; t < L - D; t += D) {
        #pragma unroll
        for (int j = 0; j < D; ++j) {
            float4 x = buf[j];
            buf[j] = ip[(size_t)(t + D + j) * U4];
            lx = fmaf(sx, lx, ox * x.x);
            ly = fmaf(sy, ly, oy * x.y);
            lz = fmaf(sz, lz, oz * x.z);
            lw = fmaf(sw, lw, ow * x.w);
        }
    }
    #pragma unroll
    for (int j = 0; j < D; ++j) {
        float4 x = buf[j];
        lx = fmaf(sx, lx, ox * x.x);
        ly = fmaf(sy, ly, oy * x.y);
        lz = fmaf(sz, lz, oz * x.z);
        lw = fmaf(sw, lw, ow * x.w);
    }

    P4[(size_t)c * P4N + (size_t)g * 64 + lane] = make_float4(lx, ly, lz, lw);
}

// ---- Kernel 2: recombine entry level, scan chunk, store ----
__global__ __launch_bounds__(64, 2) void lowpass_scan(
    const float4* __restrict__ in4,     // [B*T*U4]
    const float4* __restrict__ level04, // [U4]
    const float4* __restrict__ smooth4, // [U4]
    const float4* __restrict__ P4,      // [C * P4N]
    float4* __restrict__ out4)          // [B*T*U4]
{
    const int lane = threadIdx.x;
    const int blk  = blockIdx.x;
    const int c    = blk >> 6;
    const int g    = blk & 63;
    const int b    = g >> 2;
    const int ublk = g & 3;
    const int u4   = ublk * 64 + lane;

    const float4 smv = smooth4[u4];
    const float sx = sigmoidf(smv.x), sy = sigmoidf(smv.y),
                sz = sigmoidf(smv.z), sw = sigmoidf(smv.w);
    const float ox = 1.0f - sx, oy = 1.0f - sy, oz = 1.0f - sz, ow = 1.0f - sw;

    // s^L via repeated squaring (L = 64 = 2^6)
    float pLx = sx, pLy = sy, pLz = sz, pLw = sw;
    #pragma unroll
    for (int i = 0; i < 6; ++i) {
        pLx *= pLx; pLy *= pLy; pLz *= pLz; pLw *= pLw;
    }

    // entry level: e = level0; for i<c: e = P_i + s^L * e
    float4 l0 = level04[u4];
    float ex = l0.x, ey = l0.y, ez = l0.z, ew = l0.w;
    for (int i = 0; i < c; ++i) {
        float4 p = P4[(size_t)i * P4N + (size_t)g * 64 + lane];
        ex = fmaf(pLx, ex, p.x);
        ey = fmaf(pLy, ey, p.y);
        ez = fmaf(pLz, ez, p.z);
        ew = fmaf(pLw, ew, p.w);
    }

    const size_t base = ((size_t)b * T + (size_t)c * L) * U4 + u4;
    const float4* __restrict__ ip = in4  + base;
    float4*       __restrict__ op = out4 + base;

    float4 buf[D];
    #pragma unroll
    for (int i = 0; i < D; ++i) buf[i] = ip[(size_t)i * U4];

    int t = 0;
    for (; t < L - D; t += D) {
        #pragma unroll
        for (int j = 0; j < D; ++j) {
            float4 x = buf[j];
            buf[j] = ip[(size_t)(t + D + j) * U4];
            ex = fmaf(sx, ex, ox * x.x);
            ey = fmaf(sy, ey, oy * x.y);
            ez = fmaf(sz, ez, oz * x.z);
            ew = fmaf(sw, ew, ow * x.w);
            op[(size_t)(t + j) * U4] = make_float4(ex, ey, ez, ew);
        }
    }
    #pragma unroll
    for (int j = 0; j < D; ++j) {
        float4 x = buf[j];
        ex = fmaf(sx, ex, ox * x.x);
        ey = fmaf(sy, ey, oy * x.y);
        ez = fmaf(sz, ez, oz * x.z);
        ew = fmaf(sw, ew, ow * x.w);
        op[(size_t)(t + j) * U4] = make_float4(ex, ey, ez, ew);
    }
}

extern "C" void kernel_launch(void* const* d_in, const int* in_sizes, int n_in,
                              void* d_out, int out_size, void* d_ws, size_t ws_size,
                              hipStream_t stream) {
    const float4* in4     = (const float4*)d_in[0];  // inputs [B,T,U]
    const float4* level04 = (const float4*)d_in[1];  // level_var [1,U]
    const float4* smooth4 = (const float4*)d_in[2];  // smoothing_var [1,U]
    float4* out4          = (float4*)d_out;
    float4* P4            = (float4*)d_ws;           // C*B*U floats = 2 MiB

    dim3 block(64);
    dim3 grid(C * G);   // 32 * 64 = 2048 blocks, 8 blocks/CU

    hipLaunchKernelGGL(lowpass_partial, grid, block, 0, stream,
                       in4, smooth4, P4);
    hipLaunchKernelGGL(lowpass_scan, grid, block, 0, stream,
                       in4, level04, smooth4, P4, out4);
}